// Round 5
// baseline (2935.030 us; speedup 1.0000x reference)
//
#include <hip/hip_runtime.h>

#define L_PAD 8192
#define HS    25
#define ES    50
#define G4    100   // 4*H
#define CHUNK 64    // z-staging chunk (steps); 64*50 float2 = 25600 B = 25 lds-DMA instrs
#define LOG2E 1.44269504088896340736f

// -------- workspace layout --------
// zs2   : float2[2][L_PAD*50]   packed gate preacts: zs2[d][t*50+j] = (z[j], z[j+50])
// wstar : float2[2][50]         h* @ Wh, same packing
// cstar : float [2][25]         frozen cell state

__device__ __forceinline__ float rl_f(float v, int lane) {
    return __int_as_float(__builtin_amdgcn_readlane(__float_as_int(v), lane));
}
__device__ __forceinline__ float fast_sigmoid(float x) {
    return __builtin_amdgcn_rcpf(1.f + __builtin_amdgcn_exp2f(x * (-LOG2E)));
}
__device__ __forceinline__ float fast_tanh(float x) {
    // 2*sigmoid(2x) - 1
    return fmaf(__builtin_amdgcn_rcpf(1.f + __builtin_amdgcn_exp2f(x * (-2.f * LOG2E))), 2.f, -1.f);
}

// lane l gets its partner's value from lane l^32 (VALU permlane, not LDS bpermute).
// v_permlane32_swap_b32 semantics (round-4 bug, now fixed):
//   r[0]: lanes<32 = old0[l] (own),   lanes>=32 = old1[l-32] (PARTNER)
//   r[1]: lanes<32 = old0[l+32] (PARTNER), lanes>=32 = old1[l] (own)
// -> partner value is  hi ? r[0] : r[1].
__device__ __forceinline__ float xswap32(float v, bool hi) {
#if __has_builtin(__builtin_amdgcn_permlane32_swap)
    auto r = __builtin_amdgcn_permlane32_swap(__float_as_uint(v), __float_as_uint(v),
                                              false, false);
    return __uint_as_float(hi ? r[0] : r[1]);
#else
    return __int_as_float(__builtin_amdgcn_ds_bpermute(
        (int)(((threadIdx.x ^ 32u) & 63u) << 2), __float_as_int(v)));
#endif
}

// ---------------- kernel 1: pre-activations (parallel) ----------------
__global__ __launch_bounds__(64) void k_pre(
    const int* __restrict__ tok, const int* __restrict__ plen,
    const float* __restrict__ Ef, const float* __restrict__ Wif, const float* __restrict__ bf,
    const float* __restrict__ Eb, const float* __restrict__ Wib, const float* __restrict__ bb,
    float2* __restrict__ zs2)
{
    const int b = blockIdx.x;
    const int d = b & 1;
    const int t = b >> 1;
    const int j = threadIdx.x;
    const int len = *plen;

    int src;
    if (d == 0) src = t;
    else        src = (t < len) ? (len - 1 - t) : (L_PAD - 1 - (t - len));
    const int token = tok[src];

    const float* __restrict__ E  = d ? Eb  : Ef;
    const float* __restrict__ Wi = d ? Wib : Wif;
    const float* __restrict__ bs = d ? bb  : bf;

    __shared__ float e[ES];
    if (j < ES) e[j] = E[(size_t)token * ES + j];
    __syncthreads();
    if (j >= 50) return;

    float ax = bs[j], ay = bs[j + 50];
    float bx = 0.f,  by = 0.f;
    #pragma unroll
    for (int k = 0; k < ES; k += 2) {
        float e0 = e[k], e1 = e[k + 1];
        ax = fmaf(e0, Wi[k * G4 + j],            ax);
        ay = fmaf(e0, Wi[k * G4 + j + 50],       ay);
        bx = fmaf(e1, Wi[(k + 1) * G4 + j],      bx);
        by = fmaf(e1, Wi[(k + 1) * G4 + j + 50], by);
    }
    zs2[(size_t)d * (L_PAD * 50) + t * 50 + j] = make_float2(ax + bx, ay + by);
}

// ---------------- kernel 2: the serial recurrence (latency-bound) ----------------
// one wave per direction.
// Lane remap: lanes 0..24 own packed col p=l (gates i,g);
// lanes 32..56 own p=l-7 (cols 25..49 -> gates f,o); partner is lane l^32
// so the gate exchange is v_permlane32_swap (VALU) instead of ds_bpermute (LDS).
// Weights in LDS with bank-spread slots slot(c)=c+(c>>4): the round-3 layout's
// {c,c+16,c+32} same-bank groups (324K conflict cycles) become <=2-way (free).
// Inner loop unrolled x2: step s+1's LDS weight reads (h-independent) issue
// under step s's fma/activation chain, hiding LDS latency off the serial path.
#define SLOT(c) ((c) + ((c) >> 4))
#define WROW 106   // float2 per weight row (SLOT(99)=105 -> 106)

__global__ __launch_bounds__(64, 1)
void k_seq(
    const float* __restrict__ Whf, const float* __restrict__ Whb,
    const int* __restrict__ plen,
    const float2* __restrict__ zs2_all,
    float* __restrict__ out,
    float2* __restrict__ wstar, float* __restrict__ cstar)
{
    __shared__ float2 wl[13 * WROW];         // wl[kk*WROW + SLOT(c)] = (Wh[2kk][c], Wh[2kk+1][c])
    __shared__ float4 zch[2][CHUNK * 25];    // double-buffered z chunks: 2 x 25600 B

    const int d = blockIdx.x;
    const int l = threadIdx.x;
    const int len = *plen;
    const float* __restrict__ Wh = d ? Whb : Whf;

    const bool act = (l < 25) || (l >= 32 && l < 57);
    const int  p   = (l < 25) ? l : ((l >= 32 && l < 57) ? (l - 7) : 0);
    const bool hi32 = (l >= 32);

    // build packed weight LDS (once); writer uses col identity, reader uses p —
    // both address through SLOT so they agree.
    if (l < 50) {
        #pragma unroll
        for (int kk = 0; kk < 13; ++kk) {
            float a0 = Wh[(2 * kk) * G4 + l];
            float b0 = Wh[(2 * kk) * G4 + l + 50];
            float a1 = 0.f, b1 = 0.f;
            if (kk < 12) {
                a1 = Wh[(2 * kk + 1) * G4 + l];
                b1 = Wh[(2 * kk + 1) * G4 + l + 50];
            }
            wl[kk * WROW + SLOT(l)]      = make_float2(a0, a1);
            wl[kk * WROW + SLOT(l + 50)] = make_float2(b0, b1);
        }
    }
    __syncthreads();

    // branch-free activation constants: y-gate is tanh for lanes<32 (g), sigmoid else (o)
    const float my = hi32 ? (-LOG2E) : (-2.f * LOG2E);
    const float ca = hi32 ? 1.f : 2.f;
    const float cb = hi32 ? 0.f : -1.f;

    const int boA0 = SLOT(p);
    const int boB0 = SLOT(p + 50);

    const float4* __restrict__ zf4 = (const float4*)(zs2_all + (size_t)d * (L_PAD * 50));
    float* outp = out + d * HS + l;              // stride 50 floats per step (lanes<25 store)

    float c = 0.f, h = 0.f;   // lanes 0..24 carry real state; all lanes stay finite
                              // (hi-lane c grows at most linearly; tanh saturates; |h|<1)

    #define STAGE(BUF, CI)                                                              \
        {                                                                               \
            const float4* gsrc = zf4 + (size_t)(CI) * (CHUNK * 25) + l;                 \
            _Pragma("unroll")                                                           \
            for (int i = 0; i < 25; ++i) {                                              \
                __builtin_amdgcn_global_load_lds(                                       \
                    (const __attribute__((address_space(1))) unsigned int*)(gsrc + 64 * i), \
                    (__attribute__((address_space(3))) unsigned int*)(&zch[BUF][i * 64]),   \
                    16, 0, 0);                                                          \
            }                                                                           \
        }

    const int nch = (len + CHUNK - 1) / CHUNK;
    int buf = 0;
    if (nch > 0) {
        STAGE(0, 0)
        asm volatile("s_waitcnt vmcnt(0)" ::: "memory");
        __builtin_amdgcn_sched_barrier(0);
    }

    for (int ct = 0; ct < nch; ++ct) {
        if (ct + 1 < L_PAD / CHUNK) STAGE(buf ^ 1, ct + 1)   // prefetch next chunk (no wait)

        const int t0 = ct * CHUNK;
        const int ne = (len - t0 < CHUNK) ? (len - t0) : CHUNK;
        const float2* __restrict__ zc = (const float2*)zch[buf];

        auto step = [&](int s) {
            int boA = boA0, boB = boB0;
            asm volatile("" : "+v"(boA));         // opaque: per-step reads, no full hoist
            asm volatile("" : "+v"(boB));

            float axE = 0.f, axO = 0.f, ayE = 0.f, ayO = 0.f;
            #pragma unroll
            for (int kk = 0; kk < 13; ++kk) {
                float2 wa = wl[boA + kk * WROW];
                float2 wb = wl[boB + kk * WROW];
                float h0 = rl_f(h, 2 * kk);
                float h1 = rl_f(h, 2 * kk + 1);   // kk=12 -> lane 25 (bounded), x0 weight pad
                axE = fmaf(wa.x, h0, axE); axO = fmaf(wa.y, h1, axO);
                ayE = fmaf(wb.x, h0, ayE); ayO = fmaf(wb.y, h1, ayO);
            }
            float2 zt = zc[s * 50 + p];
            float px = (axE + axO) + zt.x;
            float py = (ayE + ayO) + zt.y;

            float sa = fast_sigmoid(px);          // i (lanes<32) / f (lanes>=32)
            float ry = __builtin_amdgcn_rcpf(1.f + __builtin_amdgcn_exp2f(py * my));
            float sb = fmaf(ry, ca, cb);          // g=tanh (lanes<32) / o=sigmoid
            float f_ = xswap32(sa, hi32);         // partner gate via VALU permlane
            float o_ = xswap32(sb, hi32);
            float nc = fmaf(f_, c, sa * sb);      // f*c + i*g
            float nh = o_ * fast_tanh(nc);
            c = nc;
            h = nh;
            if (l < 25) outp[(t0 + s) * 50] = nh; // out[t*50 + d*25 + l]
        };

        int s = 0;
        for (; s + 1 < ne; s += 2) { step(s); step(s + 1); }
        if (s < ne) step(s);

        // next chunk's DMAs landed under 64 steps of compute; drain cheaply
        asm volatile("s_waitcnt vmcnt(0)" ::: "memory");
        __builtin_amdgcn_sched_barrier(0);
        buf ^= 1;
    }

    // epilogue: w* = h* @ Wh (packed) and c* for the frozen tail
    {
        int boA = boA0, boB = boB0;
        asm volatile("" : "+v"(boA));
        asm volatile("" : "+v"(boB));
        float axE = 0.f, axO = 0.f, ayE = 0.f, ayO = 0.f;
        #pragma unroll
        for (int kk = 0; kk < 13; ++kk) {
            float2 wa = wl[boA + kk * WROW];
            float2 wb = wl[boB + kk * WROW];
            float h0 = rl_f(h, 2 * kk);
            float h1 = rl_f(h, 2 * kk + 1);
            axE = fmaf(wa.x, h0, axE); axO = fmaf(wa.y, h1, axO);
            ayE = fmaf(wb.x, h0, ayE); ayO = fmaf(wb.y, h1, ayO);
        }
        if (act)    wstar[d * 50 + p]  = make_float2(axE + axO, ayE + ayO);
        if (l < 25) cstar[d * HS + l]  = c;
    }
}

// ---------------- kernel 3: frozen-carry tail (parallel) ----------------
__global__ __launch_bounds__(256) void k_tail(
    const int* __restrict__ plen,
    const float2* __restrict__ zs2_all,
    const float2* __restrict__ wstar, const float* __restrict__ cstar,
    float* __restrict__ out)
{
    const int tid = blockIdx.x * 256 + threadIdx.x;
    if (tid >= L_PAD * 50) return;
    const int col = tid % 50;
    const int t   = tid / 50;
    const int len = *plen;
    if (t < len) return;
    const int d = col / HS;
    const int j = col % HS;

    const float2* __restrict__ z = zs2_all + (size_t)d * (L_PAD * 50);
    float2 zi = z[t * 50 + j];
    float2 zq = z[t * 50 + j + 25];
    float2 wi = wstar[d * 50 + j];
    float2 wq = wstar[d * 50 + j + 25];

    float i_ = fast_sigmoid(zi.x + wi.x);
    float g_ = fast_tanh  (zi.y + wi.y);
    float f_ = fast_sigmoid(zq.x + wq.x);
    float o_ = fast_sigmoid(zq.y + wq.y);

    float nc = fmaf(f_, cstar[d * HS + j], i_ * g_);
    out[t * 50 + col] = o_ * fast_tanh(nc);
}

extern "C" void kernel_launch(void* const* d_in, const int* in_sizes, int n_in,
                              void* d_out, int out_size, void* d_ws, size_t ws_size,
                              hipStream_t stream)
{
    const int*   tok  = (const int*)  d_in[0];
    const int*   plen = (const int*)  d_in[1];
    const float* Ef   = (const float*)d_in[2];
    const float* Wif  = (const float*)d_in[3];
    const float* Whf  = (const float*)d_in[4];
    const float* bf   = (const float*)d_in[5];
    const float* Eb   = (const float*)d_in[6];
    const float* Wib  = (const float*)d_in[7];
    const float* Whb  = (const float*)d_in[8];
    const float* bb   = (const float*)d_in[9];
    float* out = (float*)d_out;

    float2* zs2   = (float2*)d_ws;
    float2* wstar = (float2*)((char*)d_ws + (size_t)2 * L_PAD * 50 * sizeof(float2));
    float*  cstar = (float*)((char*)wstar + 100 * sizeof(float2));

    k_pre <<<2 * L_PAD, 64, 0, stream>>>(tok, plen, Ef, Wif, bf, Eb, Wib, bb, zs2);
    k_seq <<<2, 64, 0, stream>>>(Whf, Whb, plen, zs2, out, wstar, cstar);
    k_tail<<<(L_PAD * 50 + 255) / 256, 256, 0, stream>>>(plen, zs2, wstar, cstar, out);
}

// Round 6
// 2668.049 us; speedup vs baseline: 1.1001x; 1.1001x over previous
//
#include <hip/hip_runtime.h>

#define L_PAD 8192
#define HS    25
#define ES    50
#define G4    100   // 4*H
#define CHUNK 64    // z-staging chunk (steps); 64*50 float2 = 25600 B = 25 lds-DMA instrs
#define LOG2E 1.44269504088896340736f

// -------- workspace layout --------
// zs2   : float2[2][L_PAD*50]   packed gate preacts: zs2[d][t*50+j] = (z[j], z[j+50])
// wstar : float2[2][50]         h* @ Wh, same packing
// cstar : float [2][25]         frozen cell state

typedef _Float16 h2 __attribute__((ext_vector_type(2)));

__device__ __forceinline__ float fast_sigmoid(float x) {
    return __builtin_amdgcn_rcpf(1.f + __builtin_amdgcn_exp2f(x * (-LOG2E)));
}
__device__ __forceinline__ float fast_tanh(float x) {
    // 2*sigmoid(2x) - 1
    return fmaf(__builtin_amdgcn_rcpf(1.f + __builtin_amdgcn_exp2f(x * (-2.f * LOG2E))), 2.f, -1.f);
}

// lane l gets its partner's value from lane l^32 (VALU permlane) — R5-verified semantics:
//   r[0]: lanes<32 = own, lanes>=32 = partner;  r[1]: lanes<32 = partner, lanes>=32 = own
__device__ __forceinline__ float xswap32(float v, bool hi) {
#if __has_builtin(__builtin_amdgcn_permlane32_swap)
    auto r = __builtin_amdgcn_permlane32_swap(__float_as_uint(v), __float_as_uint(v),
                                              false, false);
    return __uint_as_float(hi ? r[0] : r[1]);
#else
    return __int_as_float(__builtin_amdgcn_ds_bpermute(
        (int)(((threadIdx.x ^ 32u) & 63u) << 2), __float_as_int(v)));
#endif
}

// fp16-pair dot with fp32 accumulate: products exact in fp32, acc fp32 (RNE).
__device__ __forceinline__ float fdot2u(unsigned au, unsigned bu, float c) {
#if __has_builtin(__builtin_amdgcn_fdot2)
    return __builtin_amdgcn_fdot2(__builtin_bit_cast(h2, au),
                                  __builtin_bit_cast(h2, bu), c, false);
#else
    h2 a = __builtin_bit_cast(h2, au), b = __builtin_bit_cast(h2, bu);
    return fmaf((float)a.x, (float)b.x, fmaf((float)a.y, (float)b.y, c));
#endif
}

// ---------------- kernel 1: pre-activations (parallel) ----------------
__global__ __launch_bounds__(64) void k_pre(
    const int* __restrict__ tok, const int* __restrict__ plen,
    const float* __restrict__ Ef, const float* __restrict__ Wif, const float* __restrict__ bf,
    const float* __restrict__ Eb, const float* __restrict__ Wib, const float* __restrict__ bb,
    float2* __restrict__ zs2)
{
    const int b = blockIdx.x;
    const int d = b & 1;
    const int t = b >> 1;
    const int j = threadIdx.x;
    const int len = *plen;

    int src;
    if (d == 0) src = t;
    else        src = (t < len) ? (len - 1 - t) : (L_PAD - 1 - (t - len));
    const int token = tok[src];

    const float* __restrict__ E  = d ? Eb  : Ef;
    const float* __restrict__ Wi = d ? Wib : Wif;
    const float* __restrict__ bs = d ? bb  : bf;

    __shared__ float e[ES];
    if (j < ES) e[j] = E[(size_t)token * ES + j];
    __syncthreads();
    if (j >= 50) return;

    float ax = bs[j], ay = bs[j + 50];
    float bx = 0.f,  by = 0.f;
    #pragma unroll
    for (int k = 0; k < ES; k += 2) {
        float e0 = e[k], e1 = e[k + 1];
        ax = fmaf(e0, Wi[k * G4 + j],            ax);
        ay = fmaf(e0, Wi[k * G4 + j + 50],       ay);
        bx = fmaf(e1, Wi[(k + 1) * G4 + j],      bx);
        by = fmaf(e1, Wi[(k + 1) * G4 + j + 50], by);
    }
    zs2[(size_t)d * (L_PAD * 50) + t * 50 + j] = make_float2(ax + bx, ay + by);
}

// ---------------- kernel 2: the serial recurrence (latency-bound) ----------------
// Round-6 theory: per-step time across R0..R5 tracks INSTRUCTION COUNT + exposed
// weight-fetch latency; LDS-vs-scratch placement shuffles never cut either.
// Fix: weights REG-RESIDENT as 26 fp16x2 (fits trivially, no RA pressure) and
// matvec via v_dot2_f32_f16 (exact fp32 products, fp32 acc). h broadcast as
// packed fp16 pairs: 1 cvt + 25 readlane + 13 uniform packs + 26 dot2 replaces
// {27 ds_read + 26 readlane + 52 fma}. LDS per step = one z ds_read_b64.
// Idle lanes 25..31 / 57..63 remapped to real cols 25..31 (finite, kills the
// p=0 bank pileup). Partner swap stays l^32 via permlane32_swap (R5-verified).
__global__ __launch_bounds__(64, 1)
void k_seq(
    const float* __restrict__ Whf, const float* __restrict__ Whb,
    const int* __restrict__ plen,
    const float2* __restrict__ zs2_all,
    float* __restrict__ out,
    float2* __restrict__ wstar, float* __restrict__ cstar)
{
    __shared__ float4 zch[2][CHUNK * 25];    // double-buffered z chunks: 2 x 25600 B

    const int d = blockIdx.x;
    const int l = threadIdx.x;
    const int len = *plen;
    const float* __restrict__ Wh = d ? Whb : Whf;
    const bool hi32 = (l >= 32);
    const bool act = (l < 25) || (l >= 32 && l < 57);
    // col ownership: lanes 0..24 -> p=l (i,g); lanes 32..56 -> p=l-7 (f,o);
    // idle 25..31 -> p=l, idle 57..63 -> p=l-32 (duplicate real cols, finite)
    const int p = (l < 32) ? l : ((l < 57) ? (l - 7) : (l - 32));

    // ---- weights: 26 fp16x2 regs (k-pairs), loaded once, laundered (no remat) ----
    unsigned wxu[13], wyu[13];
    {
        const float* __restrict__ Wc = Wh + p;
        #pragma unroll
        for (int kk = 0; kk < 13; ++kk) {
            float a0 = Wc[(2 * kk) * G4], b0 = Wc[(2 * kk) * G4 + 50];
            float a1 = 0.f, b1 = 0.f;
            if (kk < 12) { a1 = Wc[(2 * kk + 1) * G4]; b1 = Wc[(2 * kk + 1) * G4 + 50]; }
            h2 wa; wa.x = (_Float16)a0; wa.y = (_Float16)a1;   // RNE cvt
            h2 wb; wb.x = (_Float16)b0; wb.y = (_Float16)b1;
            wxu[kk] = __builtin_bit_cast(unsigned, wa);
            wyu[kk] = __builtin_bit_cast(unsigned, wb);
            asm volatile("" : "+v"(wxu[kk]), "+v"(wyu[kk]));
        }
    }

    // branch-free activation constants: y-gate is tanh for lanes<32 (g), sigmoid else (o)
    const float my_ = hi32 ? (-LOG2E) : (-2.f * LOG2E);
    const float ca = hi32 ? 1.f : 2.f;
    const float cb = hi32 ? 0.f : -1.f;

    const float4* __restrict__ zf4 = (const float4*)(zs2_all + (size_t)d * (L_PAD * 50));
    float* outp = out + d * HS + l;          // stride 50 floats per step (lanes<25 store)

    float c = 0.f, h = 0.f;   // all lanes bounded forever (sigmoid/tanh outputs)

    #define STAGE(BUF, CI)                                                              \
        {                                                                               \
            const float4* gsrc = zf4 + (size_t)(CI) * (CHUNK * 25) + l;                 \
            _Pragma("unroll")                                                           \
            for (int i = 0; i < 25; ++i) {                                              \
                __builtin_amdgcn_global_load_lds(                                       \
                    (const __attribute__((address_space(1))) unsigned int*)(gsrc + 64 * i), \
                    (__attribute__((address_space(3))) unsigned int*)(&zch[BUF][i * 64]),   \
                    16, 0, 0);                                                          \
            }                                                                           \
        }

    // h -> packed fp16 pairs, uniform (SGPR) domain: u_kk = (h16[2kk], h16[2kk+1])
    #define PK(KK)                                                                       \
        unsigned u##KK = ((unsigned)__builtin_amdgcn_readlane(h16i, 2 * (KK)) & 0xffffu) \
                       | ((unsigned)__builtin_amdgcn_readlane(h16i, 2 * (KK) + 1) << 16);
    #define DD(KK, X, Y) X = fdot2u(wxu[KK], u##KK, X); Y = fdot2u(wyu[KK], u##KK, Y);

    const int nch = (len + CHUNK - 1) / CHUNK;
    int buf = 0;
    if (nch > 0) {
        STAGE(0, 0)
        asm volatile("s_waitcnt vmcnt(0)" ::: "memory");
        __builtin_amdgcn_sched_barrier(0);
    }

    for (int ct = 0; ct < nch; ++ct) {
        if (ct + 1 < L_PAD / CHUNK) STAGE(buf ^ 1, ct + 1)   // prefetch next chunk (no wait)

        const int t0 = ct * CHUNK;
        const int ne = (len - t0 < CHUNK) ? (len - t0) : CHUNK;
        const float2* __restrict__ zc = (const float2*)zch[buf];

        for (int s = 0; s < ne; ++s) {
            int h16i;
            asm("v_cvt_f16_f32 %0, %1" : "=v"(h16i) : "v"(h));  // low 16 = fp16(h), RNE
            PK(0)  PK(1)  PK(2)  PK(3)  PK(4)  PK(5)
            PK(6)  PK(7)  PK(8)  PK(9)  PK(10) PK(11)
            unsigned u12 = (unsigned)__builtin_amdgcn_readlane(h16i, 24) & 0xffffu;

            float2 zt = zc[s * 50 + p];
            float x0 = zt.x, x1 = 0.f, x2 = 0.f;
            float y0 = zt.y, y1 = 0.f, y2 = 0.f;
            DD(0, x0, y0)  DD(1, x1, y1)  DD(2, x2, y2)
            DD(3, x0, y0)  DD(4, x1, y1)  DD(5, x2, y2)
            DD(6, x0, y0)  DD(7, x1, y1)  DD(8, x2, y2)
            DD(9, x0, y0)  DD(10, x1, y1) DD(11, x2, y2)
            DD(12, x0, y0)
            float px = (x0 + x1) + x2;
            float py = (y0 + y1) + y2;

            float sa = fast_sigmoid(px);          // i (lanes<32) / f (lanes>=32)
            float ry = __builtin_amdgcn_rcpf(1.f + __builtin_amdgcn_exp2f(py * my_));
            float sb = fmaf(ry, ca, cb);          // g=tanh (lanes<32) / o=sigmoid
            float f_ = xswap32(sa, hi32);
            float o_ = xswap32(sb, hi32);
            float nc = fmaf(f_, c, sa * sb);      // f*c + i*g
            float nh = o_ * fast_tanh(nc);
            c = nc;
            h = nh;
            if (l < 25) outp[(t0 + s) * 50] = nh; // out[t*50 + d*25 + l]
        }

        // next chunk's DMAs landed under 64 steps of compute; drain cheaply
        asm volatile("s_waitcnt vmcnt(0)" ::: "memory");
        __builtin_amdgcn_sched_barrier(0);
        buf ^= 1;
    }

    // epilogue: w* = h* @ Wh (same dot path) and c* for the frozen tail
    {
        int h16i;
        asm("v_cvt_f16_f32 %0, %1" : "=v"(h16i) : "v"(h));
        PK(0)  PK(1)  PK(2)  PK(3)  PK(4)  PK(5)
        PK(6)  PK(7)  PK(8)  PK(9)  PK(10) PK(11)
        unsigned u12 = (unsigned)__builtin_amdgcn_readlane(h16i, 24) & 0xffffu;

        float x0 = 0.f, x1 = 0.f, x2 = 0.f;
        float y0 = 0.f, y1 = 0.f, y2 = 0.f;
        DD(0, x0, y0)  DD(1, x1, y1)  DD(2, x2, y2)
        DD(3, x0, y0)  DD(4, x1, y1)  DD(5, x2, y2)
        DD(6, x0, y0)  DD(7, x1, y1)  DD(8, x2, y2)
        DD(9, x0, y0)  DD(10, x1, y1) DD(11, x2, y2)
        DD(12, x0, y0)
        if (act)    wstar[d * 50 + p] = make_float2((x0 + x1) + x2, (y0 + y1) + y2);
        if (l < 25) cstar[d * HS + l] = c;
    }
}

// ---------------- kernel 3: frozen-carry tail (parallel) ----------------
__global__ __launch_bounds__(256) void k_tail(
    const int* __restrict__ plen,
    const float2* __restrict__ zs2_all,
    const float2* __restrict__ wstar, const float* __restrict__ cstar,
    float* __restrict__ out)
{
    const int tid = blockIdx.x * 256 + threadIdx.x;
    if (tid >= L_PAD * 50) return;
    const int col = tid % 50;
    const int t   = tid / 50;
    const int len = *plen;
    if (t < len) return;
    const int d = col / HS;
    const int j = col % HS;

    const float2* __restrict__ z = zs2_all + (size_t)d * (L_PAD * 50);
    float2 zi = z[t * 50 + j];
    float2 zq = z[t * 50 + j + 25];
    float2 wi = wstar[d * 50 + j];
    float2 wq = wstar[d * 50 + j + 25];

    float i_ = fast_sigmoid(zi.x + wi.x);
    float g_ = fast_tanh  (zi.y + wi.y);
    float f_ = fast_sigmoid(zq.x + wq.x);
    float o_ = fast_sigmoid(zq.y + wq.y);

    float nc = fmaf(f_, cstar[d * HS + j], i_ * g_);
    out[t * 50 + col] = o_ * fast_tanh(nc);
}

extern "C" void kernel_launch(void* const* d_in, const int* in_sizes, int n_in,
                              void* d_out, int out_size, void* d_ws, size_t ws_size,
                              hipStream_t stream)
{
    const int*   tok  = (const int*)  d_in[0];
    const int*   plen = (const int*)  d_in[1];
    const float* Ef   = (const float*)d_in[2];
    const float* Wif  = (const float*)d_in[3];
    const float* Whf  = (const float*)d_in[4];
    const float* bf   = (const float*)d_in[5];
    const float* Eb   = (const float*)d_in[6];
    const float* Wib  = (const float*)d_in[7];
    const float* Whb  = (const float*)d_in[8];
    const float* bb   = (const float*)d_in[9];
    float* out = (float*)d_out;

    float2* zs2   = (float2*)d_ws;
    float2* wstar = (float2*)((char*)d_ws + (size_t)2 * L_PAD * 50 * sizeof(float2));
    float*  cstar = (float*)((char*)wstar + 100 * sizeof(float2));

    k_pre <<<2 * L_PAD, 64, 0, stream>>>(tok, plen, Ef, Wif, bf, Eb, Wib, bb, zs2);
    k_seq <<<2, 64, 0, stream>>>(Whf, Whb, plen, zs2, out, wstar, cstar);
    k_tail<<<(L_PAD * 50 + 255) / 256, 256, 0, stream>>>(plen, zs2, wstar, cstar, out);
}

// Round 7
// 2401.604 us; speedup vs baseline: 1.2221x; 1.1109x over previous
//
#include <hip/hip_runtime.h>

#define L_PAD 8192
#define HS    25
#define ES    50
#define G4    100   // 4*H
#define CHUNK 64    // z-staging chunk (steps); 64*50 float2 = 25600 B = 25 lds-DMA instrs
#define LOG2E 1.44269504088896340736f

// -------- workspace layout --------
// zs2   : float2[2][L_PAD*50]   packed gate preacts: zs2[d][t*50+j] = (z[j], z[j+50])
// wstar : float2[2][50]         h* @ Wh, same packing
// cstar : float [2][25]         frozen cell state

typedef _Float16 h2 __attribute__((ext_vector_type(2)));

__device__ __forceinline__ float fast_sigmoid(float x) {
    return __builtin_amdgcn_rcpf(1.f + __builtin_amdgcn_exp2f(x * (-LOG2E)));
}
__device__ __forceinline__ float fast_tanh(float x) {
    // 2*sigmoid(2x) - 1
    return fmaf(__builtin_amdgcn_rcpf(1.f + __builtin_amdgcn_exp2f(x * (-2.f * LOG2E))), 2.f, -1.f);
}

// lane l gets its partner's value from lane l^32 (VALU permlane) — R5-verified semantics:
//   r[0]: lanes<32 = own, lanes>=32 = partner;  r[1]: lanes<32 = partner, lanes>=32 = own
__device__ __forceinline__ float xswap32(float v, bool hi) {
#if __has_builtin(__builtin_amdgcn_permlane32_swap)
    auto r = __builtin_amdgcn_permlane32_swap(__float_as_uint(v), __float_as_uint(v),
                                              false, false);
    return __uint_as_float(hi ? r[0] : r[1]);
#else
    return __int_as_float(__builtin_amdgcn_ds_bpermute(
        (int)(((threadIdx.x ^ 32u) & 63u) << 2), __float_as_int(v)));
#endif
}

// fp16-pair dot with fp32 accumulate: products exact in fp32, acc fp32 (RNE).
__device__ __forceinline__ float fdot2u(unsigned au, unsigned bu, float c) {
#if __has_builtin(__builtin_amdgcn_fdot2)
    return __builtin_amdgcn_fdot2(__builtin_bit_cast(h2, au),
                                  __builtin_bit_cast(h2, bu), c, false);
#else
    h2 a = __builtin_bit_cast(h2, au), b = __builtin_bit_cast(h2, bu);
    return fmaf((float)a.x, (float)b.x, fmaf((float)a.y, (float)b.y, c));
#endif
}

// ---------------- kernel 1: pre-activations (parallel) ----------------
__global__ __launch_bounds__(64) void k_pre(
    const int* __restrict__ tok, const int* __restrict__ plen,
    const float* __restrict__ Ef, const float* __restrict__ Wif, const float* __restrict__ bf,
    const float* __restrict__ Eb, const float* __restrict__ Wib, const float* __restrict__ bb,
    float2* __restrict__ zs2)
{
    const int b = blockIdx.x;
    const int d = b & 1;
    const int t = b >> 1;
    const int j = threadIdx.x;
    const int len = *plen;

    int src;
    if (d == 0) src = t;
    else        src = (t < len) ? (len - 1 - t) : (L_PAD - 1 - (t - len));
    const int token = tok[src];

    const float* __restrict__ E  = d ? Eb  : Ef;
    const float* __restrict__ Wi = d ? Wib : Wif;
    const float* __restrict__ bs = d ? bb  : bf;

    __shared__ float e[ES];
    if (j < ES) e[j] = E[(size_t)token * ES + j];
    __syncthreads();
    if (j >= 50) return;

    float ax = bs[j], ay = bs[j + 50];
    float bx = 0.f,  by = 0.f;
    #pragma unroll
    for (int k = 0; k < ES; k += 2) {
        float e0 = e[k], e1 = e[k + 1];
        ax = fmaf(e0, Wi[k * G4 + j],            ax);
        ay = fmaf(e0, Wi[k * G4 + j + 50],       ay);
        bx = fmaf(e1, Wi[(k + 1) * G4 + j],      bx);
        by = fmaf(e1, Wi[(k + 1) * G4 + j + 50], by);
    }
    zs2[(size_t)d * (L_PAD * 50) + t * 50 + j] = make_float2(ax + bx, ay + by);
}

// ---------------- kernel 2: the serial recurrence (latency-bound) ----------------
// Round-7 theory: the cross-round invariant ~900 cyc/step non-VALU stall (R0..R6,
// surviving every weight/layout/swap change) is the per-step GLOBAL STORE of nh:
// loop-carried store-data register + conservative LDS aliasing vs global_load_lds
// force a per-iteration s_waitcnt vmcnt -> one HBM-ack round trip (~900 cyc,
// m126) serialized into every step. Fix: ZERO VMEM in the step loop.
//  * nh -> double-buffered LDS out-buffer (ds_write, lgkm domain);
//    bulk-flush 64x25 floats to global once per chunk, fire-and-forget,
//    acks drained at the NEXT chunk boundary (hidden under 64 steps).
//  * z ds_read software-pipelined one step ahead (h-independent).
//  * matvec: R6's verified reg-resident fp16x2 weights + v_dot2_f32_f16.
__global__ __launch_bounds__(64, 1)
void k_seq(
    const float* __restrict__ Whf, const float* __restrict__ Whb,
    const int* __restrict__ plen,
    const float2* __restrict__ zs2_all,
    float* __restrict__ out,
    float2* __restrict__ wstar, float* __restrict__ cstar)
{
    __shared__ float4 zch[2][CHUNK * 25];    // double-buffered z chunks: 2 x 25600 B
    __shared__ float  obuf[2][CHUNK * 25];   // double-buffered out accum:  2 x 6400 B

    const int d = blockIdx.x;
    const int l = threadIdx.x;
    const int len = *plen;
    const float* __restrict__ Wh = d ? Whb : Whf;
    const bool hi32 = (l >= 32);
    const bool act = (l < 25) || (l >= 32 && l < 57);
    // col ownership: lanes 0..24 -> p=l (i,g); lanes 32..56 -> p=l-7 (f,o);
    // idle 25..31 -> p=l, idle 57..63 -> p=l-32 (duplicate real cols, finite)
    const int p = (l < 32) ? l : ((l < 57) ? (l - 7) : (l - 32));

    // ---- weights: 26 fp16x2 regs (k-pairs), loaded once, laundered (no remat) ----
    unsigned wxu[13], wyu[13];
    {
        const float* __restrict__ Wc = Wh + p;
        #pragma unroll
        for (int kk = 0; kk < 13; ++kk) {
            float a0 = Wc[(2 * kk) * G4], b0 = Wc[(2 * kk) * G4 + 50];
            float a1 = 0.f, b1 = 0.f;
            if (kk < 12) { a1 = Wc[(2 * kk + 1) * G4]; b1 = Wc[(2 * kk + 1) * G4 + 50]; }
            h2 wa; wa.x = (_Float16)a0; wa.y = (_Float16)a1;   // RNE cvt
            h2 wb; wb.x = (_Float16)b0; wb.y = (_Float16)b1;
            wxu[kk] = __builtin_bit_cast(unsigned, wa);
            wyu[kk] = __builtin_bit_cast(unsigned, wb);
            asm volatile("" : "+v"(wxu[kk]), "+v"(wyu[kk]));
        }
    }

    // branch-free activation constants: y-gate is tanh for lanes<32 (g), sigmoid else (o)
    const float my_ = hi32 ? (-LOG2E) : (-2.f * LOG2E);
    const float ca = hi32 ? 1.f : 2.f;
    const float cb = hi32 ? 0.f : -1.f;

    const float4* __restrict__ zf4 = (const float4*)(zs2_all + (size_t)d * (L_PAD * 50));

    float c = 0.f, h = 0.f;   // all lanes bounded forever (sigmoid/tanh outputs)

    #define STAGE(BUF, CI)                                                              \
        {                                                                               \
            const float4* gsrc = zf4 + (size_t)(CI) * (CHUNK * 25) + l;                 \
            _Pragma("unroll")                                                           \
            for (int i = 0; i < 25; ++i) {                                              \
                __builtin_amdgcn_global_load_lds(                                       \
                    (const __attribute__((address_space(1))) unsigned int*)(gsrc + 64 * i), \
                    (__attribute__((address_space(3))) unsigned int*)(&zch[BUF][i * 64]),   \
                    16, 0, 0);                                                          \
            }                                                                           \
        }

    // h -> packed fp16 pairs, uniform (SGPR) domain: u_kk = (h16[2kk], h16[2kk+1])
    #define PK(KK)                                                                       \
        unsigned u##KK = ((unsigned)__builtin_amdgcn_readlane(h16i, 2 * (KK)) & 0xffffu) \
                       | ((unsigned)__builtin_amdgcn_readlane(h16i, 2 * (KK) + 1) << 16);
    #define DD(KK, X, Y) X = fdot2u(wxu[KK], u##KK, X); Y = fdot2u(wyu[KK], u##KK, Y);

    const int nch = (len + CHUNK - 1) / CHUNK;
    int buf = 0, ob = 0;
    if (nch > 0) {
        STAGE(0, 0)
        asm volatile("s_waitcnt vmcnt(0)" ::: "memory");
        __builtin_amdgcn_sched_barrier(0);
    }

    for (int ct = 0; ct < nch; ++ct) {
        if (ct + 1 < L_PAD / CHUNK) STAGE(buf ^ 1, ct + 1)   // prefetch next chunk (no wait)

        const int t0 = ct * CHUNK;
        const int ne = (len - t0 < CHUNK) ? (len - t0) : CHUNK;
        const float2* __restrict__ zc = (const float2*)zch[buf];

        float2 ztc = zc[p];                   // z for step 0 of this chunk
        for (int s = 0; s < ne; ++s) {
            int sn = (s + 1 < CHUNK) ? (s + 1) : s;
            float2 ztn = zc[sn * 50 + p];     // prefetch next step's z (h-independent)

            int h16i;
            asm("v_cvt_f16_f32 %0, %1" : "=v"(h16i) : "v"(h));  // low 16 = fp16(h), RNE
            PK(0)  PK(1)  PK(2)  PK(3)  PK(4)  PK(5)
            PK(6)  PK(7)  PK(8)  PK(9)  PK(10) PK(11)
            unsigned u12 = (unsigned)__builtin_amdgcn_readlane(h16i, 24) & 0xffffu;

            float x0 = ztc.x, x1 = 0.f, x2 = 0.f;
            float y0 = ztc.y, y1 = 0.f, y2 = 0.f;
            DD(0, x0, y0)  DD(1, x1, y1)  DD(2, x2, y2)
            DD(3, x0, y0)  DD(4, x1, y1)  DD(5, x2, y2)
            DD(6, x0, y0)  DD(7, x1, y1)  DD(8, x2, y2)
            DD(9, x0, y0)  DD(10, x1, y1) DD(11, x2, y2)
            DD(12, x0, y0)
            float px = (x0 + x1) + x2;
            float py = (y0 + y1) + y2;

            float sa = fast_sigmoid(px);          // i (lanes<32) / f (lanes>=32)
            float ry = __builtin_amdgcn_rcpf(1.f + __builtin_amdgcn_exp2f(py * my_));
            float sb = fmaf(ry, ca, cb);          // g=tanh (lanes<32) / o=sigmoid
            float f_ = xswap32(sa, hi32);
            float o_ = xswap32(sb, hi32);
            float nc = fmaf(f_, c, sa * sb);      // f*c + i*g
            float nh = o_ * fast_tanh(nc);
            c = nc;
            h = nh;
            if (l < 25) obuf[ob][s * 25 + l] = nh;   // LDS only — no VMEM in this loop
            ztc = ztn;
        }

        // staged loads for chunk ct+1 (and chunk ct-1's flush stores) are long done
        asm volatile("s_waitcnt vmcnt(0)" ::: "memory");
        __builtin_amdgcn_sched_barrier(0);

        // bulk-flush obuf[ob] -> out (fire-and-forget; drained at next chunk boundary)
        {
            const int E = ne * 25;
            #pragma unroll
            for (int it = 0; it < 25; ++it) {
                int e = l + 64 * it;
                if (e < E) {
                    int s_ = e / 25;
                    int j_ = e - 25 * s_;
                    out[(t0 + s_) * 50 + d * HS + j_] = obuf[ob][e];
                }
            }
        }
        ob ^= 1;
        buf ^= 1;
    }

    // epilogue: w* = h* @ Wh (same dot path) and c* for the frozen tail
    {
        int h16i;
        asm("v_cvt_f16_f32 %0, %1" : "=v"(h16i) : "v"(h));
        PK(0)  PK(1)  PK(2)  PK(3)  PK(4)  PK(5)
        PK(6)  PK(7)  PK(8)  PK(9)  PK(10) PK(11)
        unsigned u12 = (unsigned)__builtin_amdgcn_readlane(h16i, 24) & 0xffffu;

        float x0 = 0.f, x1 = 0.f, x2 = 0.f;
        float y0 = 0.f, y1 = 0.f, y2 = 0.f;
        DD(0, x0, y0)  DD(1, x1, y1)  DD(2, x2, y2)
        DD(3, x0, y0)  DD(4, x1, y1)  DD(5, x2, y2)
        DD(6, x0, y0)  DD(7, x1, y1)  DD(8, x2, y2)
        DD(9, x0, y0)  DD(10, x1, y1) DD(11, x2, y2)
        DD(12, x0, y0)
        if (act)    wstar[d * 50 + p] = make_float2((x0 + x1) + x2, (y0 + y1) + y2);
        if (l < 25) cstar[d * HS + l] = c;
    }
}

// ---------------- kernel 3: frozen-carry tail (parallel) ----------------
__global__ __launch_bounds__(256) void k_tail(
    const int* __restrict__ plen,
    const float2* __restrict__ zs2_all,
    const float2* __restrict__ wstar, const float* __restrict__ cstar,
    float* __restrict__ out)
{
    const int tid = blockIdx.x * 256 + threadIdx.x;
    if (tid >= L_PAD * 50) return;
    const int col = tid % 50;
    const int t   = tid / 50;
    const int len = *plen;
    if (t < len) return;
    const int d = col / HS;
    const int j = col % HS;

    const float2* __restrict__ z = zs2_all + (size_t)d * (L_PAD * 50);
    float2 zi = z[t * 50 + j];
    float2 zq = z[t * 50 + j + 25];
    float2 wi = wstar[d * 50 + j];
    float2 wq = wstar[d * 50 + j + 25];

    float i_ = fast_sigmoid(zi.x + wi.x);
    float g_ = fast_tanh  (zi.y + wi.y);
    float f_ = fast_sigmoid(zq.x + wq.x);
    float o_ = fast_sigmoid(zq.y + wq.y);

    float nc = fmaf(f_, cstar[d * HS + j], i_ * g_);
    out[t * 50 + col] = o_ * fast_tanh(nc);
}

extern "C" void kernel_launch(void* const* d_in, const int* in_sizes, int n_in,
                              void* d_out, int out_size, void* d_ws, size_t ws_size,
                              hipStream_t stream)
{
    const int*   tok  = (const int*)  d_in[0];
    const int*   plen = (const int*)  d_in[1];
    const float* Ef   = (const float*)d_in[2];
    const float* Wif  = (const float*)d_in[3];
    const float* Whf  = (const float*)d_in[4];
    const float* bf   = (const float*)d_in[5];
    const float* Eb   = (const float*)d_in[6];
    const float* Wib  = (const float*)d_in[7];
    const float* Whb  = (const float*)d_in[8];
    const float* bb   = (const float*)d_in[9];
    float* out = (float*)d_out;

    float2* zs2   = (float2*)d_ws;
    float2* wstar = (float2*)((char*)d_ws + (size_t)2 * L_PAD * 50 * sizeof(float2));
    float*  cstar = (float*)((char*)wstar + 100 * sizeof(float2));

    k_pre <<<2 * L_PAD, 64, 0, stream>>>(tok, plen, Ef, Wif, bf, Eb, Wib, bb, zs2);
    k_seq <<<2, 64, 0, stream>>>(Whf, Whb, plen, zs2, out, wstar, cstar);
    k_tail<<<(L_PAD * 50 + 255) / 256, 256, 0, stream>>>(plen, zs2, wstar, cstar, out);
}

// Round 9
// 1524.129 us; speedup vs baseline: 1.9257x; 1.5757x over previous
//
#include <hip/hip_runtime.h>

#define L_PAD 8192
#define HS    25
#define ES    50
#define G4    100   // 4*H
#define CHUNK 64    // z-staging chunk (steps); 64*50 float2 = 25600 B = 25 lds-DMA instrs
#define LOG2E 1.44269504088896340736f

// -------- workspace layout --------
// zs2   : float2[2][L_PAD*50]   packed gate preacts: zs2[d][t*50+j] = (z[j], z[j+50])
// wstar : float2[2][50]         h* @ Wh, same packing
// cstar : float [2][25]         frozen cell state

typedef _Float16 h2 __attribute__((ext_vector_type(2)));

__device__ __forceinline__ float fast_sigmoid(float x) {
    return __builtin_amdgcn_rcpf(1.f + __builtin_amdgcn_exp2f(x * (-LOG2E)));
}
__device__ __forceinline__ float fast_tanh(float x) {
    // 2*sigmoid(2x) - 1
    return fmaf(__builtin_amdgcn_rcpf(1.f + __builtin_amdgcn_exp2f(x * (-2.f * LOG2E))), 2.f, -1.f);
}

// lane l gets its partner's value from lane l^32 (VALU permlane) — R5-verified semantics:
//   r[0]: lanes<32 = own, lanes>=32 = partner;  r[1]: lanes<32 = partner, lanes>=32 = own
__device__ __forceinline__ float xswap32(float v, bool hi) {
#if __has_builtin(__builtin_amdgcn_permlane32_swap)
    auto r = __builtin_amdgcn_permlane32_swap(__float_as_uint(v), __float_as_uint(v),
                                              false, false);
    return __uint_as_float(hi ? r[0] : r[1]);
#else
    return __int_as_float(__builtin_amdgcn_ds_bpermute(
        (int)(((threadIdx.x ^ 32u) & 63u) << 2), __float_as_int(v)));
#endif
}

// fp16-pair dot with fp32 accumulate: products exact in fp32, acc fp32 (RNE).
__device__ __forceinline__ float fdot2u(unsigned au, unsigned bu, float c) {
#if __has_builtin(__builtin_amdgcn_fdot2)
    return __builtin_amdgcn_fdot2(__builtin_bit_cast(h2, au),
                                  __builtin_bit_cast(h2, bu), c, false);
#else
    h2 a = __builtin_bit_cast(h2, au), b = __builtin_bit_cast(h2, bu);
    return fmaf((float)a.x, (float)b.x, fmaf((float)a.y, (float)b.y, c));
#endif
}

// ---------------- kernel 1: pre-activations (parallel) ----------------
__global__ __launch_bounds__(64) void k_pre(
    const int* __restrict__ tok, const int* __restrict__ plen,
    const float* __restrict__ Ef, const float* __restrict__ Wif, const float* __restrict__ bf,
    const float* __restrict__ Eb, const float* __restrict__ Wib, const float* __restrict__ bb,
    float2* __restrict__ zs2)
{
    const int b = blockIdx.x;
    const int d = b & 1;
    const int t = b >> 1;
    const int j = threadIdx.x;
    const int len = *plen;

    int src;
    if (d == 0) src = t;
    else        src = (t < len) ? (len - 1 - t) : (L_PAD - 1 - (t - len));
    const int token = tok[src];

    const float* __restrict__ E  = d ? Eb  : Ef;
    const float* __restrict__ Wi = d ? Wib : Wif;
    const float* __restrict__ bs = d ? bb  : bf;

    __shared__ float e[ES];
    if (j < ES) e[j] = E[(size_t)token * ES + j];
    __syncthreads();
    if (j >= 50) return;

    float ax = bs[j], ay = bs[j + 50];
    float bx = 0.f,  by = 0.f;
    #pragma unroll
    for (int k = 0; k < ES; k += 2) {
        float e0 = e[k], e1 = e[k + 1];
        ax = fmaf(e0, Wi[k * G4 + j],            ax);
        ay = fmaf(e0, Wi[k * G4 + j + 50],       ay);
        bx = fmaf(e1, Wi[(k + 1) * G4 + j],      bx);
        by = fmaf(e1, Wi[(k + 1) * G4 + j + 50], by);
    }
    zs2[(size_t)d * (L_PAD * 50) + t * 50 + j] = make_float2(ax + bx, ay + by);
}

// ---------------- kernel 2: the serial recurrence (latency-bound) ----------------
// Round-9 = round-8 theory, de-risked constructs. The invariant ~900 cyc/step
// stall (survived weight placement, conflicts, swap, z-path, out-path changes
// R0..R7; VALUBusy ~10% of active CU) is attributed to the h-broadcast:
// 25 v_readlane = 25 VALU->SGPR writes each followed by a consumer ->
// multi-cycle hazard wait-states, ~400-500 cyc/step, present in EVERY round.
// Fix: broadcast with zero SGPR involvement:
//   cvt h->fp16 (plain cast); ds_swizzle xor-1 (ISA-doc common pattern) pairs
//   (h[2k],h[2k+1]) on even lanes; 13x ds_bpermute with uniform addr = lane 2k
//   -> every lane holds all 13 packed pairs in VGPRs (crossbar broadcast,
//   conflict-free, pipelined, no SGPR hazards). dot2s consume VGPR operands.
// Everything else = R7 verified structure (chunked DMA staging, LDS out-buffer
// + per-chunk bulk flush, reg-resident fp16x2 weights, permlane gate swap).
__global__ __launch_bounds__(64, 1)
void k_seq(
    const float* __restrict__ Whf, const float* __restrict__ Whb,
    const int* __restrict__ plen,
    const float2* __restrict__ zs2_all,
    float* __restrict__ out,
    float2* __restrict__ wstar, float* __restrict__ cstar)
{
    __shared__ float4 zch[2][CHUNK * 25];    // double-buffered z chunks: 2 x 25600 B
    __shared__ float  obuf[2][CHUNK * 25];   // double-buffered out accum:  2 x 6400 B

    const int d = blockIdx.x;
    const int l = threadIdx.x;
    const int len = *plen;
    const float* __restrict__ Wh = d ? Whb : Whf;
    const bool hi32 = (l >= 32);
    const bool act = (l < 25) || (l >= 32 && l < 57);
    // col ownership: lanes 0..24 -> p=l (i,g); lanes 32..56 -> p=l-7 (f,o);
    // idle 25..31 -> p=l, idle 57..63 -> p=l-32 (duplicate real cols)
    const int p = (l < 32) ? l : ((l < 57) ? (l - 7) : (l - 32));

    // ---- weights: 26 fp16x2 regs (k-pairs), loaded once, laundered (no remat) ----
    unsigned wxu[13], wyu[13];
    {
        const float* __restrict__ Wc = Wh + p;
        #pragma unroll
        for (int kk = 0; kk < 13; ++kk) {
            float a0 = Wc[(2 * kk) * G4], b0 = Wc[(2 * kk) * G4 + 50];
            float a1 = 0.f, b1 = 0.f;
            if (kk < 12) { a1 = Wc[(2 * kk + 1) * G4]; b1 = Wc[(2 * kk + 1) * G4 + 50]; }
            h2 wa; wa.x = (_Float16)a0; wa.y = (_Float16)a1;   // RNE cvt
            h2 wb; wb.x = (_Float16)b0; wb.y = (_Float16)b1;
            wxu[kk] = __builtin_bit_cast(unsigned, wa);
            wyu[kk] = __builtin_bit_cast(unsigned, wb);
            asm volatile("" : "+v"(wxu[kk]), "+v"(wyu[kk]));
        }
    }

    // branch-free activation constants: y-gate is tanh for lanes<32 (g), sigmoid else (o)
    const float my_ = hi32 ? (-LOG2E) : (-2.f * LOG2E);
    const float ca = hi32 ? 1.f : 2.f;
    const float cb = hi32 ? 0.f : -1.f;

    const float4* __restrict__ zf4 = (const float4*)(zs2_all + (size_t)d * (L_PAD * 50));

    float c = 0.f, h = 0.f;   // all lanes bounded forever (sigmoid/tanh outputs)

    #define STAGE(BUF, CI)                                                              \
        {                                                                               \
            const float4* gsrc = zf4 + (size_t)(CI) * (CHUNK * 25) + l;                 \
            _Pragma("unroll")                                                           \
            for (int i = 0; i < 25; ++i) {                                              \
                __builtin_amdgcn_global_load_lds(                                       \
                    (const __attribute__((address_space(1))) unsigned int*)(gsrc + 64 * i), \
                    (__attribute__((address_space(3))) unsigned int*)(&zch[BUF][i * 64]),   \
                    16, 0, 0);                                                          \
            }                                                                           \
        }

    // h-broadcast, zero-SGPR: cvt (plain cast) + ds_swizzle xor-1 pair-pack +
    // 13 bpermute broadcasts. Even lane 2k holds (h16[2k] | h16[2k+1]<<16);
    // bpermute addr 8*kk broadcasts lane 2kk's pack to all 64 lanes.
    #define GATHER                                                                       \
        int h16i = (int)(unsigned short)__builtin_bit_cast(unsigned short, (_Float16)h); \
        int hsh  = __builtin_amdgcn_ds_swizzle(h16i, 0x041F);  /* lane l <- l^1 */       \
        int hpk  = (int)(((unsigned)hsh << 16) | ((unsigned)h16i & 0xffffu));            \
        unsigned u0  = (unsigned)__builtin_amdgcn_ds_bpermute(0,   hpk);                 \
        unsigned u1  = (unsigned)__builtin_amdgcn_ds_bpermute(8,   hpk);                 \
        unsigned u2  = (unsigned)__builtin_amdgcn_ds_bpermute(16,  hpk);                 \
        unsigned u3  = (unsigned)__builtin_amdgcn_ds_bpermute(24,  hpk);                 \
        unsigned u4  = (unsigned)__builtin_amdgcn_ds_bpermute(32,  hpk);                 \
        unsigned u5  = (unsigned)__builtin_amdgcn_ds_bpermute(40,  hpk);                 \
        unsigned u6  = (unsigned)__builtin_amdgcn_ds_bpermute(48,  hpk);                 \
        unsigned u7  = (unsigned)__builtin_amdgcn_ds_bpermute(56,  hpk);                 \
        unsigned u8  = (unsigned)__builtin_amdgcn_ds_bpermute(64,  hpk);                 \
        unsigned u9  = (unsigned)__builtin_amdgcn_ds_bpermute(72,  hpk);                 \
        unsigned u10 = (unsigned)__builtin_amdgcn_ds_bpermute(80,  hpk);                 \
        unsigned u11 = (unsigned)__builtin_amdgcn_ds_bpermute(88,  hpk);                 \
        unsigned u12 = (unsigned)__builtin_amdgcn_ds_bpermute(96,  hpk);
    #define DD(KK, X, Y) X = fdot2u(wxu[KK], u##KK, X); Y = fdot2u(wyu[KK], u##KK, Y);

    const int nch = (len + CHUNK - 1) / CHUNK;
    int buf = 0, ob = 0;
    if (nch > 0) {
        STAGE(0, 0)
        asm volatile("s_waitcnt vmcnt(0)" ::: "memory");
        __builtin_amdgcn_sched_barrier(0);
    }

    for (int ct = 0; ct < nch; ++ct) {
        if (ct + 1 < L_PAD / CHUNK) STAGE(buf ^ 1, ct + 1)   // prefetch next chunk (no wait)

        const int t0 = ct * CHUNK;
        const int ne = (len - t0 < CHUNK) ? (len - t0) : CHUNK;
        const float2* __restrict__ zc = (const float2*)zch[buf];

        float2 ztc = zc[p];                   // z for step 0 of this chunk
        for (int s = 0; s < ne; ++s) {
            int sn = (s + 1 < CHUNK) ? (s + 1) : s;
            float2 ztn = zc[sn * 50 + p];     // prefetch next step's z (h-independent)

            GATHER

            float x0 = ztc.x, x1 = 0.f, x2 = 0.f;
            float y0 = ztc.y, y1 = 0.f, y2 = 0.f;
            DD(0, x0, y0)  DD(1, x1, y1)  DD(2, x2, y2)
            DD(3, x0, y0)  DD(4, x1, y1)  DD(5, x2, y2)
            DD(6, x0, y0)  DD(7, x1, y1)  DD(8, x2, y2)
            DD(9, x0, y0)  DD(10, x1, y1) DD(11, x2, y2)
            DD(12, x0, y0)
            float px = (x0 + x1) + x2;
            float py = (y0 + y1) + y2;

            float sa = fast_sigmoid(px);          // i (lanes<32) / f (lanes>=32)
            float ry = __builtin_amdgcn_rcpf(1.f + __builtin_amdgcn_exp2f(py * my_));
            float sb = fmaf(ry, ca, cb);          // g=tanh (lanes<32) / o=sigmoid
            float f_ = xswap32(sa, hi32);
            float o_ = xswap32(sb, hi32);
            float nc = fmaf(f_, c, sa * sb);      // f*c + i*g
            float nh = o_ * fast_tanh(nc);
            c = nc;
            h = nh;
            if (l < 25) obuf[ob][s * 25 + l] = nh;   // LDS only — no VMEM in this loop
            ztc = ztn;
        }

        // staged loads for chunk ct+1 (and chunk ct-1's flush stores) are long done
        asm volatile("s_waitcnt vmcnt(0)" ::: "memory");
        __builtin_amdgcn_sched_barrier(0);

        // bulk-flush obuf[ob] -> out (fire-and-forget; drained at next chunk boundary)
        {
            const int E = ne * 25;
            #pragma unroll
            for (int it = 0; it < 25; ++it) {
                int e = l + 64 * it;
                if (e < E) {
                    int s_ = e / 25;
                    int j_ = e - 25 * s_;
                    out[(t0 + s_) * 50 + d * HS + j_] = obuf[ob][e];
                }
            }
        }
        ob ^= 1;
        buf ^= 1;
    }

    // epilogue: w* = h* @ Wh (same dot path) and c* for the frozen tail
    {
        GATHER
        float x0 = 0.f, x1 = 0.f, x2 = 0.f;
        float y0 = 0.f, y1 = 0.f, y2 = 0.f;
        DD(0, x0, y0)  DD(1, x1, y1)  DD(2, x2, y2)
        DD(3, x0, y0)  DD(4, x1, y1)  DD(5, x2, y2)
        DD(6, x0, y0)  DD(7, x1, y1)  DD(8, x2, y2)
        DD(9, x0, y0)  DD(10, x1, y1) DD(11, x2, y2)
        DD(12, x0, y0)
        if (act)    wstar[d * 50 + p] = make_float2((x0 + x1) + x2, (y0 + y1) + y2);
        if (l < 25) cstar[d * HS + l] = c;
    }
}

// ---------------- kernel 3: frozen-carry tail (parallel) ----------------
__global__ __launch_bounds__(256) void k_tail(
    const int* __restrict__ plen,
    const float2* __restrict__ zs2_all,
    const float2* __restrict__ wstar, const float* __restrict__ cstar,
    float* __restrict__ out)
{
    const int tid = blockIdx.x * 256 + threadIdx.x;
    if (tid >= L_PAD * 50) return;
    const int col = tid % 50;
    const int t   = tid / 50;
    const int len = *plen;
    if (t < len) return;
    const int d = col / HS;
    const int j = col % HS;

    const float2* __restrict__ z = zs2_all + (size_t)d * (L_PAD * 50);
    float2 zi = z[t * 50 + j];
    float2 zq = z[t * 50 + j + 25];
    float2 wi = wstar[d * 50 + j];
    float2 wq = wstar[d * 50 + j + 25];

    float i_ = fast_sigmoid(zi.x + wi.x);
    float g_ = fast_tanh  (zi.y + wi.y);
    float f_ = fast_sigmoid(zq.x + wq.x);
    float o_ = fast_sigmoid(zq.y + wq.y);

    float nc = fmaf(f_, cstar[d * HS + j], i_ * g_);
    out[t * 50 + col] = o_ * fast_tanh(nc);
}

extern "C" void kernel_launch(void* const* d_in, const int* in_sizes, int n_in,
                              void* d_out, int out_size, void* d_ws, size_t ws_size,
                              hipStream_t stream)
{
    const int*   tok  = (const int*)  d_in[0];
    const int*   plen = (const int*)  d_in[1];
    const float* Ef   = (const float*)d_in[2];
    const float* Wif  = (const float*)d_in[3];
    const float* Whf  = (const float*)d_in[4];
    const float* bf   = (const float*)d_in[5];
    const float* Eb   = (const float*)d_in[6];
    const float* Wib  = (const float*)d_in[7];
    const float* Whb  = (const float*)d_in[8];
    const float* bb   = (const float*)d_in[9];
    float* out = (float*)d_out;

    float2* zs2   = (float2*)d_ws;
    float2* wstar = (float2*)((char*)d_ws + (size_t)2 * L_PAD * 50 * sizeof(float2));
    float*  cstar = (float*)((char*)wstar + 100 * sizeof(float2));

    k_pre <<<2 * L_PAD, 64, 0, stream>>>(tok, plen, Ef, Wif, bf, Eb, Wib, bb, zs2);
    k_seq <<<2, 64, 0, stream>>>(Whf, Whb, plen, zs2, out, wstar, cstar);
    k_tail<<<(L_PAD * 50 + 255) / 256, 256, 0, stream>>>(plen, zs2, wstar, cstar, out);
}

// Round 11
// 1379.695 us; speedup vs baseline: 2.1273x; 1.1047x over previous
//
#include <hip/hip_runtime.h>

#define L_PAD 8192
#define HS    25
#define ES    50
#define G4    100   // 4*H
#define CHUNK 64    // z-staging chunk (steps); 64*50 float2 = 25600 B = 25 lds-DMA instrs
#define LOG2E 1.44269504088896340736f

// -------- workspace layout --------
// zs2   : float2[2][L_PAD*50]   packed gate preacts: zs2[d][t*50+j] = (z[j], z[j+50])
// wstar : float2[2][50]         h* @ Wh, same packing
// cstar : float [2][25]         frozen cell state

typedef _Float16 h2 __attribute__((ext_vector_type(2)));
typedef int4 i4a __attribute__((may_alias));
typedef int  ia  __attribute__((may_alias));

__device__ __forceinline__ float fast_sigmoid(float x) {
    return __builtin_amdgcn_rcpf(1.f + __builtin_amdgcn_exp2f(x * (-LOG2E)));
}
__device__ __forceinline__ float fast_tanh(float x) {
    // 2*sigmoid(2x) - 1
    return fmaf(__builtin_amdgcn_rcpf(1.f + __builtin_amdgcn_exp2f(x * (-2.f * LOG2E))), 2.f, -1.f);
}

// lane l gets its partner's value from lane l^32 (VALU permlane) — R5-verified semantics:
//   r[0]: lanes<32 = own, lanes>=32 = partner;  r[1]: lanes<32 = partner, lanes>=32 = own
__device__ __forceinline__ float xswap32(float v, bool hi) {
#if __has_builtin(__builtin_amdgcn_permlane32_swap)
    auto r = __builtin_amdgcn_permlane32_swap(__float_as_uint(v), __float_as_uint(v),
                                              false, false);
    return __uint_as_float(hi ? r[0] : r[1]);
#else
    return __int_as_float(__builtin_amdgcn_ds_bpermute(
        (int)(((threadIdx.x ^ 32u) & 63u) << 2), __float_as_int(v)));
#endif
}

// fp16-pair dot with fp32 accumulate: products exact in fp32, acc fp32 (RNE).
__device__ __forceinline__ float fdot2u(unsigned au, unsigned bu, float c) {
#if __has_builtin(__builtin_amdgcn_fdot2)
    return __builtin_amdgcn_fdot2(__builtin_bit_cast(h2, au),
                                  __builtin_bit_cast(h2, bu), c, false);
#else
    h2 a = __builtin_bit_cast(h2, au), b = __builtin_bit_cast(h2, bu);
    return fmaf((float)a.x, (float)b.x, fmaf((float)a.y, (float)b.y, c));
#endif
}

// ---------------- kernel 1: pre-activations (parallel) ----------------
__global__ __launch_bounds__(64) void k_pre(
    const int* __restrict__ tok, const int* __restrict__ plen,
    const float* __restrict__ Ef, const float* __restrict__ Wif, const float* __restrict__ bf,
    const float* __restrict__ Eb, const float* __restrict__ Wib, const float* __restrict__ bb,
    float2* __restrict__ zs2)
{
    const int b = blockIdx.x;
    const int d = b & 1;
    const int t = b >> 1;
    const int j = threadIdx.x;
    const int len = *plen;

    int src;
    if (d == 0) src = t;
    else        src = (t < len) ? (len - 1 - t) : (L_PAD - 1 - (t - len));
    const int token = tok[src];

    const float* __restrict__ E  = d ? Eb  : Ef;
    const float* __restrict__ Wi = d ? Wib : Wif;
    const float* __restrict__ bs = d ? bb  : bf;

    __shared__ float e[ES];
    if (j < ES) e[j] = E[(size_t)token * ES + j];
    __syncthreads();
    if (j >= 50) return;

    float ax = bs[j], ay = bs[j + 50];
    float bx = 0.f,  by = 0.f;
    #pragma unroll
    for (int k = 0; k < ES; k += 2) {
        float e0 = e[k], e1 = e[k + 1];
        ax = fmaf(e0, Wi[k * G4 + j],            ax);
        ay = fmaf(e0, Wi[k * G4 + j + 50],       ay);
        bx = fmaf(e1, Wi[(k + 1) * G4 + j],      bx);
        by = fmaf(e1, Wi[(k + 1) * G4 + j + 50], by);
    }
    zs2[(size_t)d * (L_PAD * 50) + t * 50 + j] = make_float2(ax + bx, ay + by);
}

// ---------------- kernel 2: the serial recurrence (latency-bound) ----------------
// R9 confirmed: SGPR-hazard h-broadcast was ~350 cyc/step. R10's one-trip
// broadcast FAILED (absmax 1.3e-2): the read-back type-punned ushort-store /
// int4-load — TBAA let the compiler hoist/CSE the loads above the store, so the
// recurrence consumed stale h. Round-11 = same structure with the aliasing made
// compiler-visible: may_alias typedefs on the read pointers + an empty asm
// memory fence between the hb store and the packed reads (zero instructions,
// pins program order). HW side is safe regardless: same-wave DS ops retire in
// FIFO order (the mechanism that makes ds_bpermute coherent).
// Broadcast = ds_write_b16 own h16 -> 3x ds_read_b128 + 1x ds_read_b32 at
// wave-uniform addresses (broadcast, conflict-free). Adjacent fp16 = pair-pack
// free. Reads issue at END of step s, consumed at s+1 (R9's proven pipeline).
// Dword 12 high half = lane-25 bounded garbage x zero weight pad = exact 0.
__global__ __launch_bounds__(64, 1)
void k_seq(
    const float* __restrict__ Whf, const float* __restrict__ Whb,
    const int* __restrict__ plen,
    const float2* __restrict__ zs2_all,
    float* __restrict__ out,
    float2* __restrict__ wstar, float* __restrict__ cstar)
{
    __shared__ float4 zch[2][CHUNK * 25];    // double-buffered z chunks: 2 x 25600 B
    __shared__ float  obuf[2][CHUNK * 25];   // double-buffered out accum:  2 x 6400 B
    __shared__ __attribute__((aligned(16))) unsigned short hb[64];  // h16 broadcast (128 B)

    const int d = blockIdx.x;
    const int l = threadIdx.x;
    const int len = *plen;
    const float* __restrict__ Wh = d ? Whb : Whf;
    const bool hi32 = (l >= 32);
    const bool act = (l < 25) || (l >= 32 && l < 57);
    // col ownership: lanes 0..24 -> p=l (i,g); lanes 32..56 -> p=l-7 (f,o);
    // idle 25..31 -> p=l, idle 57..63 -> p=l-32 (duplicate real cols)
    const int p = (l < 32) ? l : ((l < 57) ? (l - 7) : (l - 32));

    // ---- weights: 26 fp16x2 regs (k-pairs), loaded once, laundered (no remat) ----
    unsigned wxu[13], wyu[13];
    {
        const float* __restrict__ Wc = Wh + p;
        #pragma unroll
        for (int kk = 0; kk < 13; ++kk) {
            float a0 = Wc[(2 * kk) * G4], b0 = Wc[(2 * kk) * G4 + 50];
            float a1 = 0.f, b1 = 0.f;
            if (kk < 12) { a1 = Wc[(2 * kk + 1) * G4]; b1 = Wc[(2 * kk + 1) * G4 + 50]; }
            h2 wa; wa.x = (_Float16)a0; wa.y = (_Float16)a1;   // RNE cvt
            h2 wb; wb.x = (_Float16)b0; wb.y = (_Float16)b1;
            wxu[kk] = __builtin_bit_cast(unsigned, wa);
            wyu[kk] = __builtin_bit_cast(unsigned, wb);
            asm volatile("" : "+v"(wxu[kk]), "+v"(wyu[kk]));
        }
    }

    // branch-free activation constants: y-gate is tanh for lanes<32 (g), sigmoid else (o)
    const float my_ = hi32 ? (-LOG2E) : (-2.f * LOG2E);
    const float ca = hi32 ? 1.f : 2.f;
    const float cb = hi32 ? 0.f : -1.f;

    const float4* __restrict__ zf4 = (const float4*)(zs2_all + (size_t)d * (L_PAD * 50));

    float c = 0.f, h = 0.f;   // all lanes bounded forever (sigmoid/tanh outputs)

    #define STAGE(BUF, CI)                                                              \
        {                                                                               \
            const float4* gsrc = zf4 + (size_t)(CI) * (CHUNK * 25) + l;                 \
            _Pragma("unroll")                                                           \
            for (int i = 0; i < 25; ++i) {                                              \
                __builtin_amdgcn_global_load_lds(                                       \
                    (const __attribute__((address_space(1))) unsigned int*)(gsrc + 64 * i), \
                    (__attribute__((address_space(3))) unsigned int*)(&zch[BUF][i * 64]),   \
                    16, 0, 0);                                                          \
            }                                                                           \
        }

    // one-trip h-broadcast: write own fp16, fence (compiler order), read 13
    // packed dwords at uniform addresses. Issued at the end of a step; u*
    // consumed at the start of the next step.
    unsigned u0, u1, u2, u3, u4, u5, u6, u7, u8, u9, u10, u11, u12;
    #define EMIT_H(HV)                                                                   \
        {                                                                                \
            hb[l] = __builtin_bit_cast(unsigned short, (_Float16)(HV));                  \
            asm volatile("" ::: "memory");   /* pin read-after-write program order */    \
            const i4a* hb4 = (const i4a*)hb;                                             \
            int4 ra = hb4[0];                                                            \
            int4 rb = hb4[1];                                                            \
            int4 rc = hb4[2];                                                            \
            int  rd = ((const ia*)hb)[12];                                               \
            u0 = (unsigned)ra.x;  u1 = (unsigned)ra.y;  u2  = (unsigned)ra.z;            \
            u3 = (unsigned)ra.w;  u4 = (unsigned)rb.x;  u5  = (unsigned)rb.y;            \
            u6 = (unsigned)rb.z;  u7 = (unsigned)rb.w;  u8  = (unsigned)rc.x;            \
            u9 = (unsigned)rc.y;  u10 = (unsigned)rc.z; u11 = (unsigned)rc.w;            \
            u12 = (unsigned)rd;                                                          \
        }
    #define DD(KK, X, Y) X = fdot2u(wxu[KK], u##KK, X); Y = fdot2u(wyu[KK], u##KK, Y);

    const int nch = (len + CHUNK - 1) / CHUNK;
    int buf = 0, ob = 0;
    if (nch > 0) {
        STAGE(0, 0)
        asm volatile("s_waitcnt vmcnt(0)" ::: "memory");
        __builtin_amdgcn_sched_barrier(0);
    }
    EMIT_H(h)   // pipeline fill: broadcast of h=0

    for (int ct = 0; ct < nch; ++ct) {
        if (ct + 1 < L_PAD / CHUNK) STAGE(buf ^ 1, ct + 1)   // prefetch next chunk (no wait)

        const int t0 = ct * CHUNK;
        const int ne = (len - t0 < CHUNK) ? (len - t0) : CHUNK;
        const float2* __restrict__ zc = (const float2*)zch[buf];

        float2 ztc = zc[p];                   // z for step 0 of this chunk
        for (int s = 0; s < ne; ++s) {
            int sn = (s + 1 < CHUNK) ? (s + 1) : s;
            float2 ztn = zc[sn * 50 + p];     // prefetch next step's z (h-independent)

            float x0 = ztc.x, x1 = 0.f, x2 = 0.f;
            float y0 = ztc.y, y1 = 0.f, y2 = 0.f;
            DD(0, x0, y0)  DD(1, x1, y1)  DD(2, x2, y2)
            DD(3, x0, y0)  DD(4, x1, y1)  DD(5, x2, y2)
            DD(6, x0, y0)  DD(7, x1, y1)  DD(8, x2, y2)
            DD(9, x0, y0)  DD(10, x1, y1) DD(11, x2, y2)
            DD(12, x0, y0)
            float px = (x0 + x1) + x2;
            float py = (y0 + y1) + y2;

            float sa = fast_sigmoid(px);          // i (lanes<32) / f (lanes>=32)
            float ry = __builtin_amdgcn_rcpf(1.f + __builtin_amdgcn_exp2f(py * my_));
            float sb = fmaf(ry, ca, cb);          // g=tanh (lanes<32) / o=sigmoid
            float f_ = xswap32(sa, hi32);
            float o_ = xswap32(sb, hi32);
            float nc = fmaf(f_, c, sa * sb);      // f*c + i*g
            float nh = o_ * fast_tanh(nc);
            c = nc;
            h = nh;
            EMIT_H(nh)                            // next step's broadcast (1 DS trip)
            if (l < 25) obuf[ob][s * 25 + l] = nh;   // LDS only — no VMEM in this loop
            ztc = ztn;
        }

        // staged loads for chunk ct+1 (and chunk ct-1's flush stores) are long done
        asm volatile("s_waitcnt vmcnt(0)" ::: "memory");
        __builtin_amdgcn_sched_barrier(0);

        // bulk-flush obuf[ob] -> out (fire-and-forget; drained at next chunk boundary)
        {
            const int E = ne * 25;
            #pragma unroll
            for (int it = 0; it < 25; ++it) {
                int e = l + 64 * it;
                if (e < E) {
                    int s_ = e / 25;
                    int j_ = e - 25 * s_;
                    out[(t0 + s_) * 50 + d * HS + j_] = obuf[ob][e];
                }
            }
        }
        ob ^= 1;
        buf ^= 1;
    }

    // epilogue: w* = h* @ Wh — u* already hold the final h (issued by the last
    // EMIT_H in the loop); c* for the frozen tail
    {
        float x0 = 0.f, x1 = 0.f, x2 = 0.f;
        float y0 = 0.f, y1 = 0.f, y2 = 0.f;
        DD(0, x0, y0)  DD(1, x1, y1)  DD(2, x2, y2)
        DD(3, x0, y0)  DD(4, x1, y1)  DD(5, x2, y2)
        DD(6, x0, y0)  DD(7, x1, y1)  DD(8, x2, y2)
        DD(9, x0, y0)  DD(10, x1, y1) DD(11, x2, y2)
        DD(12, x0, y0)
        if (act)    wstar[d * 50 + p] = make_float2((x0 + x1) + x2, (y0 + y1) + y2);
        if (l < 25) cstar[d * HS + l] = c;
    }
}

// ---------------- kernel 3: frozen-carry tail (parallel) ----------------
__global__ __launch_bounds__(256) void k_tail(
    const int* __restrict__ plen,
    const float2* __restrict__ zs2_all,
    const float2* __restrict__ wstar, const float* __restrict__ cstar,
    float* __restrict__ out)
{
    const int tid = blockIdx.x * 256 + threadIdx.x;
    if (tid >= L_PAD * 50) return;
    const int col = tid % 50;
    const int t   = tid / 50;
    const int len = *plen;
    if (t < len) return;
    const int d = col / HS;
    const int j = col % HS;

    const float2* __restrict__ z = zs2_all + (size_t)d * (L_PAD * 50);
    float2 zi = z[t * 50 + j];
    float2 zq = z[t * 50 + j + 25];
    float2 wi = wstar[d * 50 + j];
    float2 wq = wstar[d * 50 + j + 25];

    float i_ = fast_sigmoid(zi.x + wi.x);
    float g_ = fast_tanh  (zi.y + wi.y);
    float f_ = fast_sigmoid(zq.x + wq.x);
    float o_ = fast_sigmoid(zq.y + wq.y);

    float nc = fmaf(f_, cstar[d * HS + j], i_ * g_);
    out[t * 50 + col] = o_ * fast_tanh(nc);
}

extern "C" void kernel_launch(void* const* d_in, const int* in_sizes, int n_in,
                              void* d_out, int out_size, void* d_ws, size_t ws_size,
                              hipStream_t stream)
{
    const int*   tok  = (const int*)  d_in[0];
    const int*   plen = (const int*)  d_in[1];
    const float* Ef   = (const float*)d_in[2];
    const float* Wif  = (const float*)d_in[3];
    const float* Whf  = (const float*)d_in[4];
    const float* bf   = (const float*)d_in[5];
    const float* Eb   = (const float*)d_in[6];
    const float* Wib  = (const float*)d_in[7];
    const float* Whb  = (const float*)d_in[8];
    const float* bb   = (const float*)d_in[9];
    float* out = (float*)d_out;

    float2* zs2   = (float2*)d_ws;
    float2* wstar = (float2*)((char*)d_ws + (size_t)2 * L_PAD * 50 * sizeof(float2));
    float*  cstar = (float*)((char*)wstar + 100 * sizeof(float2));

    k_pre <<<2 * L_PAD, 64, 0, stream>>>(tok, plen, Ef, Wif, bf, Eb, Wib, bb, zs2);
    k_seq <<<2, 64, 0, stream>>>(Whf, Whb, plen, zs2, out, wstar, cstar);
    k_tail<<<(L_PAD * 50 + 255) / 256, 256, 0, stream>>>(plen, zs2, wstar, cstar, out);
}

// Round 13
// 1374.718 us; speedup vs baseline: 2.1350x; 1.0036x over previous
//
#include <hip/hip_runtime.h>

#define L_PAD 8192
#define HS    25
#define ES    50
#define G4    100   // 4*H
#define CHUNK 64    // z-staging chunk (steps); 64*50 float2 = 25600 B = 25 lds-DMA instrs
#define LOG2E 1.44269504088896340736f

// -------- workspace layout --------
// zs2   : float2[2][L_PAD*50]   packed gate preacts, PRE-SCALED for exp2:
//         zs2[d][t*50+j] = ( (z[j])*(-LOG2E), (z[j+50])*sy(j) )
//         sy(j) = -2*LOG2E for j<25 (tanh gate), -LOG2E otherwise (sigmoid)
// wstar : float2[2][50]         h* @ Wh, same (scaled) packing
// cstar : float [2][25]         frozen cell state (unscaled)

typedef _Float16 h2 __attribute__((ext_vector_type(2)));
typedef int4 i4a __attribute__((may_alias));
typedef int  ia  __attribute__((may_alias));

__device__ __forceinline__ float fast_tanh(float x) {
    // 2*sigmoid(2x) - 1
    return fmaf(__builtin_amdgcn_rcpf(1.f + __builtin_amdgcn_exp2f(x * (-2.f * LOG2E))), 2.f, -1.f);
}
// sigmoid of a PRE-SCALED argument X = x*(-LOG2E)
__device__ __forceinline__ float sig_pre(float X) {
    return __builtin_amdgcn_rcpf(1.f + __builtin_amdgcn_exp2f(X));
}

// lane l gets its partner's value from lane l^32 (VALU permlane) — R5-verified semantics:
//   r[0]: lanes<32 = own, lanes>=32 = partner;  r[1]: lanes<32 = partner, lanes>=32 = own
__device__ __forceinline__ float xswap32(float v, bool hi) {
#if __has_builtin(__builtin_amdgcn_permlane32_swap)
    auto r = __builtin_amdgcn_permlane32_swap(__float_as_uint(v), __float_as_uint(v),
                                              false, false);
    return __uint_as_float(hi ? r[0] : r[1]);
#else
    return __int_as_float(__builtin_amdgcn_ds_bpermute(
        (int)(((threadIdx.x ^ 32u) & 63u) << 2), __float_as_int(v)));
#endif
}

// fp16-pair dot with fp32 accumulate: products exact in fp32, acc fp32 (RNE).
__device__ __forceinline__ float fdot2u(unsigned au, unsigned bu, float c) {
#if __has_builtin(__builtin_amdgcn_fdot2)
    return __builtin_amdgcn_fdot2(__builtin_bit_cast(h2, au),
                                  __builtin_bit_cast(h2, bu), c, false);
#else
    h2 a = __builtin_bit_cast(h2, au), b = __builtin_bit_cast(h2, bu);
    return fmaf((float)a.x, (float)b.x, fmaf((float)a.y, (float)b.y, c));
#endif
}

// ---------------- kernel 1: pre-activations (parallel) ----------------
__global__ __launch_bounds__(64) void k_pre(
    const int* __restrict__ tok, const int* __restrict__ plen,
    const float* __restrict__ Ef, const float* __restrict__ Wif, const float* __restrict__ bf,
    const float* __restrict__ Eb, const float* __restrict__ Wib, const float* __restrict__ bb,
    float2* __restrict__ zs2)
{
    const int b = blockIdx.x;
    const int d = b & 1;
    const int t = b >> 1;
    const int j = threadIdx.x;
    const int len = *plen;

    int src;
    if (d == 0) src = t;
    else        src = (t < len) ? (len - 1 - t) : (L_PAD - 1 - (t - len));
    const int token = tok[src];

    const float* __restrict__ E  = d ? Eb  : Ef;
    const float* __restrict__ Wi = d ? Wib : Wif;
    const float* __restrict__ bs = d ? bb  : bf;

    __shared__ float e[ES];
    if (j < ES) e[j] = E[(size_t)token * ES + j];
    __syncthreads();
    if (j >= 50) return;

    float ax = bs[j], ay = bs[j + 50];
    float bx = 0.f,  by = 0.f;
    #pragma unroll
    for (int k = 0; k < ES; k += 2) {
        float e0 = e[k], e1 = e[k + 1];
        ax = fmaf(e0, Wi[k * G4 + j],            ax);
        ay = fmaf(e0, Wi[k * G4 + j + 50],       ay);
        bx = fmaf(e1, Wi[(k + 1) * G4 + j],      bx);
        by = fmaf(e1, Wi[(k + 1) * G4 + j + 50], by);
    }
    // pre-scale for exp2: x-gates (i/f) sigmoid -> -LOG2E; y-gates: g(tanh) -> -2LOG2E, o -> -LOG2E
    const float sy = (j < 25) ? (-2.f * LOG2E) : (-LOG2E);
    zs2[(size_t)d * (L_PAD * 50) + t * 50 + j] =
        make_float2((ax + bx) * (-LOG2E), (ay + by) * sy);
}

// ---------------- kernel 2: the serial recurrence (latency-bound) ----------------
// R12 post-mortem: DPP builtin = 2/2 container failures -> permanently banned.
// Refined LDS model: R11's write+read broadcast is ~110-130 cyc exposed (pipe
// in-order, reads flow behind the write), NOT two full trips; R12's one-trip
// design (+34 issue ops) would have been net-negative. R11 budget @513 cyc/step:
// issue ~140, broadcast ~110, activation chain ~95, slop ~150.
// Round-13 trims (verified constructs only):
//  * exp2 pre-scaling folded into z (k_pre) and the fp16 weights -> the two
//    critical-path v_muls before each v_exp vanish (numerics: identical exp2
//    arguments; wstar/k_tail use the scaled convention consistently).
//  * #pragma unroll 2 on the step loop (cross-step scheduling room).
// Everything else byte-identical to R11 (best verified, 1283 us).
__global__ __launch_bounds__(64, 1)
void k_seq(
    const float* __restrict__ Whf, const float* __restrict__ Whb,
    const int* __restrict__ plen,
    const float2* __restrict__ zs2_all,
    float* __restrict__ out,
    float2* __restrict__ wstar, float* __restrict__ cstar)
{
    __shared__ float4 zch[2][CHUNK * 25];    // double-buffered z chunks: 2 x 25600 B
    __shared__ float  obuf[2][CHUNK * 25];   // double-buffered out accum:  2 x 6400 B
    __shared__ __attribute__((aligned(16))) unsigned short hb[64];  // h16 broadcast (128 B)

    const int d = blockIdx.x;
    const int l = threadIdx.x;
    const int len = *plen;
    const float* __restrict__ Wh = d ? Whb : Whf;
    const bool hi32 = (l >= 32);
    const bool act = (l < 25) || (l >= 32 && l < 57);
    // col ownership: lanes 0..24 -> p=l (i,g); lanes 32..56 -> p=l-7 (f,o);
    // idle 25..31 -> p=l, idle 57..63 -> p=l-32 (duplicate real cols)
    const int p = (l < 32) ? l : ((l < 57) ? (l - 7) : (l - 32));

    // branch-free activation constants: y-gate is tanh for lanes<32 (g), sigmoid else (o)
    const float my_ = hi32 ? (-LOG2E) : (-2.f * LOG2E);
    const float ca = hi32 ? 1.f : 2.f;
    const float cb = hi32 ? 0.f : -1.f;

    // ---- weights: 26 fp16x2 regs (k-pairs), PRE-SCALED, loaded once, laundered ----
    unsigned wxu[13], wyu[13];
    {
        const float* __restrict__ Wc = Wh + p;
        #pragma unroll
        for (int kk = 0; kk < 13; ++kk) {
            float a0 = Wc[(2 * kk) * G4] * (-LOG2E);
            float b0 = Wc[(2 * kk) * G4 + 50] * my_;
            float a1 = 0.f, b1 = 0.f;
            if (kk < 12) {
                a1 = Wc[(2 * kk + 1) * G4] * (-LOG2E);
                b1 = Wc[(2 * kk + 1) * G4 + 50] * my_;
            }
            h2 wa; wa.x = (_Float16)a0; wa.y = (_Float16)a1;   // RNE cvt
            h2 wb; wb.x = (_Float16)b0; wb.y = (_Float16)b1;
            wxu[kk] = __builtin_bit_cast(unsigned, wa);
            wyu[kk] = __builtin_bit_cast(unsigned, wb);
            asm volatile("" : "+v"(wxu[kk]), "+v"(wyu[kk]));
        }
    }

    const float4* __restrict__ zf4 = (const float4*)(zs2_all + (size_t)d * (L_PAD * 50));

    float c = 0.f, h = 0.f;   // all lanes bounded forever (sigmoid/tanh outputs)

    #define STAGE(BUF, CI)                                                              \
        {                                                                               \
            const float4* gsrc = zf4 + (size_t)(CI) * (CHUNK * 25) + l;                 \
            _Pragma("unroll")                                                           \
            for (int i = 0; i < 25; ++i) {                                              \
                __builtin_amdgcn_global_load_lds(                                       \
                    (const __attribute__((address_space(1))) unsigned int*)(gsrc + 64 * i), \
                    (__attribute__((address_space(3))) unsigned int*)(&zch[BUF][i * 64]),   \
                    16, 0, 0);                                                          \
            }                                                                           \
        }

    // one-trip-ish h-broadcast (R11-verified): write own fp16, fence (compiler
    // order), read 13 packed dwords at uniform addresses. Issued at the end of
    // a step; u* consumed at the start of the next step.
    unsigned u0, u1, u2, u3, u4, u5, u6, u7, u8, u9, u10, u11, u12;
    #define EMIT_H(HV)                                                                   \
        {                                                                                \
            hb[l] = __builtin_bit_cast(unsigned short, (_Float16)(HV));                  \
            asm volatile("" ::: "memory");   /* pin read-after-write program order */    \
            const i4a* hb4 = (const i4a*)hb;                                             \
            int4 ra = hb4[0];                                                            \
            int4 rb = hb4[1];                                                            \
            int4 rc = hb4[2];                                                            \
            int  rd = ((const ia*)hb)[12];                                               \
            u0 = (unsigned)ra.x;  u1 = (unsigned)ra.y;  u2  = (unsigned)ra.z;            \
            u3 = (unsigned)ra.w;  u4 = (unsigned)rb.x;  u5  = (unsigned)rb.y;            \
            u6 = (unsigned)rb.z;  u7 = (unsigned)rb.w;  u8  = (unsigned)rc.x;            \
            u9 = (unsigned)rc.y;  u10 = (unsigned)rc.z; u11 = (unsigned)rc.w;            \
            u12 = (unsigned)rd;                                                          \
        }
    #define DD(KK, X, Y) X = fdot2u(wxu[KK], u##KK, X); Y = fdot2u(wyu[KK], u##KK, Y);

    const int nch = (len + CHUNK - 1) / CHUNK;
    int buf = 0, ob = 0;
    if (nch > 0) {
        STAGE(0, 0)
        asm volatile("s_waitcnt vmcnt(0)" ::: "memory");
        __builtin_amdgcn_sched_barrier(0);
    }
    EMIT_H(h)   // pipeline fill: broadcast of h=0

    for (int ct = 0; ct < nch; ++ct) {
        if (ct + 1 < L_PAD / CHUNK) STAGE(buf ^ 1, ct + 1)   // prefetch next chunk (no wait)

        const int t0 = ct * CHUNK;
        const int ne = (len - t0 < CHUNK) ? (len - t0) : CHUNK;
        const float2* __restrict__ zc = (const float2*)zch[buf];

        float2 ztc = zc[p];                   // z for step 0 of this chunk
        #pragma unroll 2
        for (int s = 0; s < ne; ++s) {
            int sn = (s + 1 < CHUNK) ? (s + 1) : s;
            float2 ztn = zc[sn * 50 + p];     // prefetch next step's z (h-independent)

            float x0 = ztc.x, x1 = 0.f, x2 = 0.f;
            float y0 = ztc.y, y1 = 0.f, y2 = 0.f;
            DD(0, x0, y0)  DD(1, x1, y1)  DD(2, x2, y2)
            DD(3, x0, y0)  DD(4, x1, y1)  DD(5, x2, y2)
            DD(6, x0, y0)  DD(7, x1, y1)  DD(8, x2, y2)
            DD(9, x0, y0)  DD(10, x1, y1) DD(11, x2, y2)
            DD(12, x0, y0)
            float px = (x0 + x1) + x2;        // already exp2-scaled
            float py = (y0 + y1) + y2;

            float sa = sig_pre(px);               // i (lanes<32) / f (lanes>=32)
            float ry = sig_pre(py);
            float sb = fmaf(ry, ca, cb);          // g=tanh (lanes<32) / o=sigmoid
            float f_ = xswap32(sa, hi32);
            float o_ = xswap32(sb, hi32);
            float nc = fmaf(f_, c, sa * sb);      // f*c + i*g
            float nh = o_ * fast_tanh(nc);
            c = nc;
            h = nh;
            EMIT_H(nh)                            // next step's broadcast
            if (l < 25) obuf[ob][s * 25 + l] = nh;   // LDS only — no VMEM in this loop
            ztc = ztn;
        }

        // staged loads for chunk ct+1 (and chunk ct-1's flush stores) are long done
        asm volatile("s_waitcnt vmcnt(0)" ::: "memory");
        __builtin_amdgcn_sched_barrier(0);

        // bulk-flush obuf[ob] -> out (fire-and-forget; drained at next chunk boundary)
        {
            const int E = ne * 25;
            #pragma unroll
            for (int it = 0; it < 25; ++it) {
                int e = l + 64 * it;
                if (e < E) {
                    int s_ = e / 25;
                    int j_ = e - 25 * s_;
                    out[(t0 + s_) * 50 + d * HS + j_] = obuf[ob][e];
                }
            }
        }
        ob ^= 1;
        buf ^= 1;
    }

    // epilogue: w* = h* @ Wh (scaled convention, consumed by k_tail) — u* already
    // hold the final h (issued by the last EMIT_H); c* for the frozen tail
    {
        float x0 = 0.f, x1 = 0.f, x2 = 0.f;
        float y0 = 0.f, y1 = 0.f, y2 = 0.f;
        DD(0, x0, y0)  DD(1, x1, y1)  DD(2, x2, y2)
        DD(3, x0, y0)  DD(4, x1, y1)  DD(5, x2, y2)
        DD(6, x0, y0)  DD(7, x1, y1)  DD(8, x2, y2)
        DD(9, x0, y0)  DD(10, x1, y1) DD(11, x2, y2)
        DD(12, x0, y0)
        if (act)    wstar[d * 50 + p] = make_float2((x0 + x1) + x2, (y0 + y1) + y2);
        if (l < 25) cstar[d * HS + l] = c;
    }
}

// ---------------- kernel 3: frozen-carry tail (parallel) ----------------
// consumes the SCALED z/wstar convention: exp2 args are already scaled.
__global__ __launch_bounds__(256) void k_tail(
    const int* __restrict__ plen,
    const float2* __restrict__ zs2_all,
    const float2* __restrict__ wstar, const float* __restrict__ cstar,
    float* __restrict__ out)
{
    const int tid = blockIdx.x * 256 + threadIdx.x;
    if (tid >= L_PAD * 50) return;
    const int col = tid % 50;
    const int t   = tid / 50;
    const int len = *plen;
    if (t < len) return;
    const int d = col / HS;
    const int j = col % HS;

    const float2* __restrict__ z = zs2_all + (size_t)d * (L_PAD * 50);
    float2 zi = z[t * 50 + j];
    float2 zq = z[t * 50 + j + 25];
    float2 wi = wstar[d * 50 + j];
    float2 wq = wstar[d * 50 + j + 25];

    float i_ = sig_pre(zi.x + wi.x);
    float g_ = fmaf(sig_pre(zi.y + wi.y), 2.f, -1.f);   // tanh, pre-scaled arg
    float f_ = sig_pre(zq.x + wq.x);
    float o_ = sig_pre(zq.y + wq.y);

    float nc = fmaf(f_, cstar[d * HS + j], i_ * g_);
    out[t * 50 + col] = o_ * fast_tanh(nc);
}

extern "C" void kernel_launch(void* const* d_in, const int* in_sizes, int n_in,
                              void* d_out, int out_size, void* d_ws, size_t ws_size,
                              hipStream_t stream)
{
    const int*   tok  = (const int*)  d_in[0];
    const int*   plen = (const int*)  d_in[1];
    const float* Ef   = (const float*)d_in[2];
    const float* Wif  = (const float*)d_in[3];
    const float* Whf  = (const float*)d_in[4];
    const float* bf   = (const float*)d_in[5];
    const float* Eb   = (const float*)d_in[6];
    const float* Wib  = (const float*)d_in[7];
    const float* Whb  = (const float*)d_in[8];
    const float* bb   = (const float*)d_in[9];
    float* out = (float*)d_out;

    float2* zs2   = (float2*)d_ws;
    float2* wstar = (float2*)((char*)d_ws + (size_t)2 * L_PAD * 50 * sizeof(float2));
    float*  cstar = (float*)((char*)wstar + 100 * sizeof(float2));

    k_pre <<<2 * L_PAD, 64, 0, stream>>>(tok, plen, Ef, Wif, bf, Eb, Wib, bb, zs2);
    k_seq <<<2, 64, 0, stream>>>(Whf, Whb, plen, zs2, out, wstar, cstar);
    k_tail<<<(L_PAD * 50 + 255) / 256, 256, 0, stream>>>(plen, zs2, wstar, cstar, out);
}